// Round 5
// baseline (445.940 us; speedup 1.0000x reference)
//
#include <hip/hip_runtime.h>

#define BATCH      4096
#define FILTER_NUM 1024
#define REL_CNT    19
#define REL_DIM    1024
#define SLAB       (FILTER_NUM * REL_CNT)   // 19456 floats per batch
#define ITERS      (SLAB / (256 * 4))       // 19 exactly

typedef float vf4 __attribute__((ext_vector_type(4)));

// Kernel 1: V[f,r] = sum_e U[f,e] * R[r,e]   (V = U @ R^T, [1024 x 19])
__global__ __launch_bounds__(256) void compute_V_kernel(
        const float* __restrict__ U,   // [FILTER_NUM, REL_DIM]
        const float* __restrict__ Rm,  // [REL_CNT, REL_DIM]
        float* __restrict__ V)         // [FILTER_NUM, REL_CNT]
{
    const int f   = blockIdx.x;
    const int tid = threadIdx.x;

    float acc[REL_CNT];
#pragma unroll
    for (int r = 0; r < REL_CNT; ++r) acc[r] = 0.0f;

    const float* __restrict__ Urow = U + (size_t)f * REL_DIM;
    for (int e = tid; e < REL_DIM; e += 256) {
        const float u = Urow[e];
#pragma unroll
        for (int r = 0; r < REL_CNT; ++r)
            acc[r] = fmaf(u, Rm[r * REL_DIM + e], acc[r]);
    }

    __shared__ float s[4][REL_CNT];
    const int lane = tid & 63;
    const int wave = tid >> 6;
#pragma unroll
    for (int r = 0; r < REL_CNT; ++r) {
        float v = acc[r];
#pragma unroll
        for (int off = 32; off > 0; off >>= 1)
            v += __shfl_down(v, off, 64);
        if (lane == 0) s[wave][r] = v;
    }
    __syncthreads();
    if (tid < REL_CNT)
        V[f * REL_CNT + tid] = s[0][tid] + s[1][tid] + s[2][tid] + s[3][tid];
}

// Kernel 2 — DISCRIMINATING PROBE (R3 kernel + one extra NT read pass).
// Pass 0 streams the conv slab into a dead accumulator (kept live via
// asm volatile so the loads can't be DCE'd); pass 1 is the real compute,
// identical to Round 3 but with NT restored (R4 showed cached is -24us).
// NT = no-allocate, so pass 1 re-reads from HBM: marginal HBM bytes x2.
//   Theory A (harness floor, score~55us):  dur ~ 450-465 us
//   Theory B (score~195us @ 1.6 TB/s cap): dur ~ 560-610 us
__global__ __launch_bounds__(256, 4) void score_kernel(
        const float* __restrict__ conv,  // [BATCH, FILTER_NUM, REL_CNT]
        const float* __restrict__ V,     // [FILTER_NUM, REL_CNT] flat
        float* __restrict__ out)         // [BATCH, REL_CNT]
{
    const int b    = blockIdx.x;
    const int tid  = threadIdx.x;
    const int lane = tid & 63;
    const int wave = tid >> 6;

    const vf4* __restrict__ c4 = (const vf4*)(conv + (size_t)b * SLAB);
    const vf4* __restrict__ v4 = (const vf4*)V;

    const int o = (4 * tid) % REL_CNT;

    // ---- pass 0: dummy NT stream of the whole slab (loads kept live) ----
    float dead = 0.0f;
#pragma unroll
    for (int iter = 0; iter < ITERS; ++iter) {
        const int idx = iter * 256 + tid;
        const vf4 x = __builtin_nontemporal_load(&c4[idx]);
        dead += x.x + x.y + x.z + x.w;
    }
    asm volatile("" :: "v"(dead));   // keep pass-0 loads live (no DCE)

    // ---- pass 1: real compute (identical to Round 3, NT restored) ----
    float acc[REL_CNT];
#pragma unroll
    for (int j = 0; j < REL_CNT; ++j) acc[j] = 0.0f;

#pragma unroll
    for (int iter = 0; iter < ITERS; ++iter) {
        const int idx = iter * 256 + tid;
        const vf4 v = v4[idx];                              // L2-resident
        const vf4 x = __builtin_nontemporal_load(&c4[idx]); // HBM stream
        const int j0 = (17 * iter + 0) % REL_CNT;
        const int j1 = (17 * iter + 1) % REL_CNT;
        const int j2 = (17 * iter + 2) % REL_CNT;
        const int j3 = (17 * iter + 3) % REL_CNT;
        acc[j0] = fmaf(x.x, v.x, acc[j0]);
        acc[j1] = fmaf(x.y, v.y, acc[j1]);
        acc[j2] = fmaf(x.z, v.z, acc[j2]);
        acc[j3] = fmaf(x.w, v.w, acc[j3]);
    }

    // ---- low-LDS rotation-aware reduction (5.4 KB), same as Round 3 ----
    __shared__ float s[64][REL_CNT + 1];   // 5120 B, padded (20 floats/row)
    __shared__ float s2[4 * REL_CNT];      // 304 B

    const int rr = tid % REL_CNT;
    const int gg = tid / REL_CNT;
    float part = 0.0f;

#pragma unroll
    for (int p = 0; p < 4; ++p) {
        if (wave == p) {
#pragma unroll
            for (int j = 0; j < REL_CNT; ++j) {
                int r = o + j; if (r >= REL_CNT) r -= REL_CNT;
                s[lane][r] = acc[j];
            }
        }
        __syncthreads();
        if (tid < 4 * REL_CNT) {
            float sum = 0.0f;
#pragma unroll
            for (int i = 0; i < 16; ++i)
                sum += s[gg * 16 + i][rr];
            part += sum;
        }
        __syncthreads();   // readers done before next phase overwrites s
    }

    if (tid < 4 * REL_CNT) s2[gg * REL_CNT + rr] = part;
    __syncthreads();
    if (tid < REL_CNT) {
        float sum = 0.0f;
#pragma unroll
        for (int g = 0; g < 4; ++g) sum += s2[g * REL_CNT + tid];
        out[b * REL_CNT + tid] = sum;
    }
}

extern "C" void kernel_launch(void* const* d_in, const int* in_sizes, int n_in,
                              void* d_out, int out_size, void* d_ws, size_t ws_size,
                              hipStream_t stream) {
    // setup_inputs order: conv_output [B,F,R], R_output [R,E], U [F,E] — all fp32
    const float* conv = (const float*)d_in[0];
    const float* Rm   = (const float*)d_in[1];
    const float* U    = (const float*)d_in[2];
    float*       out  = (float*)d_out;
    float*       V    = (float*)d_ws;   // FILTER_NUM*REL_CNT floats

    compute_V_kernel<<<FILTER_NUM, 256, 0, stream>>>(U, Rm, V);
    score_kernel<<<BATCH, 256, 0, stream>>>(conv, V, out);
}

// Round 6
// 406.766 us; speedup vs baseline: 1.0963x; 1.0963x over previous
//
#include <hip/hip_runtime.h>

#define BATCH      4096
#define FILTER_NUM 1024
#define REL_CNT    19
#define REL_DIM    1024
#define SLAB       (FILTER_NUM * REL_CNT)   // 19456 floats per batch
#define ITERS      (SLAB / (256 * 4))       // 19 exactly

typedef float vf4 __attribute__((ext_vector_type(4)));

// Kernel 1: V[f,r] = sum_e U[f,e] * R[r,e]   (V = U @ R^T, [1024 x 19])
__global__ __launch_bounds__(256) void compute_V_kernel(
        const float* __restrict__ U,   // [FILTER_NUM, REL_DIM]
        const float* __restrict__ Rm,  // [REL_CNT, REL_DIM]
        float* __restrict__ V)         // [FILTER_NUM, REL_CNT]
{
    const int f   = blockIdx.x;
    const int tid = threadIdx.x;

    float acc[REL_CNT];
#pragma unroll
    for (int r = 0; r < REL_CNT; ++r) acc[r] = 0.0f;

    const float* __restrict__ Urow = U + (size_t)f * REL_DIM;
    for (int e = tid; e < REL_DIM; e += 256) {
        const float u = Urow[e];
#pragma unroll
        for (int r = 0; r < REL_CNT; ++r)
            acc[r] = fmaf(u, Rm[r * REL_DIM + e], acc[r]);
    }

    __shared__ float s[4][REL_CNT];
    const int lane = tid & 63;
    const int wave = tid >> 6;
#pragma unroll
    for (int r = 0; r < REL_CNT; ++r) {
        float v = acc[r];
#pragma unroll
        for (int off = 32; off > 0; off >>= 1)
            v += __shfl_down(v, off, 64);
        if (lane == 0) s[wave][r] = v;
    }
    __syncthreads();
    if (tid < REL_CNT)
        V[f * REL_CNT + tid] = s[0][tid] + s[1][tid] + s[2][tid] + s[3][tid];
}

// Kernel 2: one batch slab per block — FINAL (Round-3 structure, probe pass
// removed). Session findings baked in:
//  - NT conv loads REQUIRED: cached loads cost +24 us (R4 A/B) via L2/L3
//    pollution against harness traffic.
//  - conv stream is at the HBM roofline: R5 probe showed a duplicate
//    318.8 MB NT pass costs only ~40 us marginal -> this kernel ~51 us.
//  - Structure-insensitive (dual-slab / occupancy / LDS size all within
//    noise) because the 405 us window is ~350 us harness-fixed.
// Static phase rotation: element k of float4 idx has
//   r = (17*iter + o + k) % 19,  o = (4*tid) % 19.
__global__ __launch_bounds__(256, 4) void score_kernel(
        const float* __restrict__ conv,  // [BATCH, FILTER_NUM, REL_CNT]
        const float* __restrict__ V,     // [FILTER_NUM, REL_CNT] flat
        float* __restrict__ out)         // [BATCH, REL_CNT]
{
    const int b    = blockIdx.x;
    const int tid  = threadIdx.x;
    const int lane = tid & 63;
    const int wave = tid >> 6;

    const vf4* __restrict__ c4 = (const vf4*)(conv + (size_t)b * SLAB);
    const vf4* __restrict__ v4 = (const vf4*)V;

    const int o = (4 * tid) % REL_CNT;

    float acc[REL_CNT];
#pragma unroll
    for (int j = 0; j < REL_CNT; ++j) acc[j] = 0.0f;

#pragma unroll
    for (int iter = 0; iter < ITERS; ++iter) {
        const int idx = iter * 256 + tid;
        const vf4 v = v4[idx];                              // L2-resident (76 KB)
        const vf4 x = __builtin_nontemporal_load(&c4[idx]); // HBM stream, no-alloc
        const int j0 = (17 * iter + 0) % REL_CNT;
        const int j1 = (17 * iter + 1) % REL_CNT;
        const int j2 = (17 * iter + 2) % REL_CNT;
        const int j3 = (17 * iter + 3) % REL_CNT;
        acc[j0] = fmaf(x.x, v.x, acc[j0]);
        acc[j1] = fmaf(x.y, v.y, acc[j1]);
        acc[j2] = fmaf(x.z, v.z, acc[j2]);
        acc[j3] = fmaf(x.w, v.w, acc[j3]);
    }

    // ---- low-LDS rotation-aware reduction (5.4 KB) ----
    __shared__ float s[64][REL_CNT + 1];   // 5120 B, padded (20 floats/row)
    __shared__ float s2[4 * REL_CNT];      // 304 B

    const int rr = tid % REL_CNT;
    const int gg = tid / REL_CNT;
    float part = 0.0f;

#pragma unroll
    for (int p = 0; p < 4; ++p) {
        if (wave == p) {
#pragma unroll
            for (int j = 0; j < REL_CNT; ++j) {
                int r = o + j; if (r >= REL_CNT) r -= REL_CNT;
                s[lane][r] = acc[j];
            }
        }
        __syncthreads();
        if (tid < 4 * REL_CNT) {
            float sum = 0.0f;
#pragma unroll
            for (int i = 0; i < 16; ++i)
                sum += s[gg * 16 + i][rr];
            part += sum;
        }
        __syncthreads();   // readers done before next phase overwrites s
    }

    if (tid < 4 * REL_CNT) s2[gg * REL_CNT + rr] = part;
    __syncthreads();
    if (tid < REL_CNT) {
        float sum = 0.0f;
#pragma unroll
        for (int g = 0; g < 4; ++g) sum += s2[g * REL_CNT + tid];
        out[b * REL_CNT + tid] = sum;
    }
}

extern "C" void kernel_launch(void* const* d_in, const int* in_sizes, int n_in,
                              void* d_out, int out_size, void* d_ws, size_t ws_size,
                              hipStream_t stream) {
    // setup_inputs order: conv_output [B,F,R], R_output [R,E], U [F,E] — all fp32
    const float* conv = (const float*)d_in[0];
    const float* Rm   = (const float*)d_in[1];
    const float* U    = (const float*)d_in[2];
    float*       out  = (float*)d_out;
    float*       V    = (float*)d_ws;   // FILTER_NUM*REL_CNT floats

    compute_V_kernel<<<FILTER_NUM, 256, 0, stream>>>(U, Rm, V);
    score_kernel<<<BATCH, 256, 0, stream>>>(conv, V, out);
}